// Round 3
// baseline (757.137 us; speedup 1.0000x reference)
//
#include <hip/hip_runtime.h>
#include <hip/hip_bf16.h>

typedef unsigned short u16;
typedef __bf16 bf16x8 __attribute__((ext_vector_type(8)));
typedef float f32x4 __attribute__((ext_vector_type(4)));
typedef u16 u16x4 __attribute__((ext_vector_type(4)));

__device__ __forceinline__ u16 f2bf(float f) {
    __bf16 h = (__bf16)f;
    return __builtin_bit_cast(u16, h);
}
__device__ __forceinline__ float bf2f(u16 u) {
    __bf16 h = __builtin_bit_cast(__bf16, u);
    return (float)h;
}

#define MFMA16(a, b, c) __builtin_amdgcn_mfma_f32_16x16x32_bf16(a, b, c, 0, 0, 0)

__device__ __forceinline__ void gload_lds16(const u16* g, u16* l) {
    __builtin_amdgcn_global_load_lds((const __attribute__((address_space(1))) void*)g,
                                     (__attribute__((address_space(3))) void*)l, 16, 0, 0);
}

// ---------------- cast x -> bf16 (vectorized x4) ----------------
__global__ __launch_bounds__(256) void cast_bf16(const float* __restrict__ in,
                                                 u16* __restrict__ out, int n4) {
    int i = blockIdx.x * 256 + threadIdx.x;
    if (i >= n4) return;
    float4 a = ((const float4*)in)[i];
    u16x4 u;
    u[0] = f2bf(a.x); u[1] = f2bf(a.y); u[2] = f2bf(a.z); u[3] = f2bf(a.w);
    ((u16x4*)out)[i] = u;
}

// ------------- transpose + cast: in[R][C] fp32 -> out[C][R] bf16 -------------
__global__ __launch_bounds__(256) void transpose_cast(const float* __restrict__ in,
                                                      u16* __restrict__ out, int R, int C) {
    __shared__ u16 tile[64][65];
    const int tc = blockIdx.x * 64, tr = blockIdx.y * 64;
    const int lr = threadIdx.x >> 6, lc = threadIdx.x & 63;
#pragma unroll
    for (int i = 0; i < 16; i++) {
        int r = i * 4 + lr;
        tile[r][lc] = f2bf(in[(size_t)(tr + r) * C + tc + lc]);
    }
    __syncthreads();
#pragma unroll
    for (int i = 0; i < 16; i++) {
        int r = i * 4 + lr;
        out[(size_t)(tc + r) * R + tr + lc] = tile[lc][r];
    }
}

// ---------------- GEMM: C[M,N] = A[M,K] * Bt[N,K]^T  (bf16 in, f32 acc) ----------------
// 128x128 tile, BK=32, 4 waves (2x2), 4x4 16x16x32 MFMA frags per wave.
template <int F32OUT>
__global__ __launch_bounds__(256) void gemm_bt(const u16* __restrict__ A,
                                               const u16* __restrict__ Bt,
                                               void* __restrict__ C, int M, int N, int K) {
    __shared__ u16 As[128 * 32];
    __shared__ u16 Bs[128 * 32];
    const int tid = threadIdx.x;
    const int wave = tid >> 6, lane = tid & 63;
    const int l15 = lane & 15, l16 = lane >> 4;
    const int row0 = blockIdx.y * 128, col0 = blockIdx.x * 128;
    const int wr = (wave >> 1) * 64, wc = (wave & 1) * 64;
    // staging chunks: chunk c covers row c>>2, cols (c&3)*8 .. +8 of the 128x32 tile
    const int c0 = wave * 128 + lane;
    const int c1 = c0 + 64;
    const int rA0 = c0 >> 2, ccA0 = (c0 & 3) * 8;
    const int rA1 = c1 >> 2, ccA1 = (c1 & 3) * 8;
    const u16* Ab = A + (size_t)row0 * K;
    const u16* Bb = Bt + (size_t)col0 * K;

    f32x4 acc[4][4] = {};

    for (int kt = 0; kt < K; kt += 32) {
        __syncthreads();
        gload_lds16(Ab + (size_t)rA0 * K + kt + ccA0, &As[(wave * 2 + 0) * 512]);
        gload_lds16(Ab + (size_t)rA1 * K + kt + ccA1, &As[(wave * 2 + 1) * 512]);
        gload_lds16(Bb + (size_t)rA0 * K + kt + ccA0, &Bs[(wave * 2 + 0) * 512]);
        gload_lds16(Bb + (size_t)rA1 * K + kt + ccA1, &Bs[(wave * 2 + 1) * 512]);
        __syncthreads();
        bf16x8 af[4], bfr[4];
#pragma unroll
        for (int m = 0; m < 4; m++)
            af[m] = *(const bf16x8*)&As[(wr + m * 16 + l15) * 32 + l16 * 8];
#pragma unroll
        for (int n = 0; n < 4; n++)
            bfr[n] = *(const bf16x8*)&Bs[(wc + n * 16 + l15) * 32 + l16 * 8];
#pragma unroll
        for (int m = 0; m < 4; m++)
#pragma unroll
            for (int n = 0; n < 4; n++)
                acc[m][n] = MFMA16(af[m], bfr[n], acc[m][n]);
    }

#pragma unroll
    for (int m = 0; m < 4; m++)
#pragma unroll
        for (int n = 0; n < 4; n++)
#pragma unroll
            for (int r = 0; r < 4; r++) {
                size_t ci = (size_t)(row0 + wr + m * 16 + l16 * 4 + r) * N +
                            (col0 + wc + n * 16 + l15);
                if (F32OUT)
                    ((float*)C)[ci] = acc[m][n][r];
                else
                    ((u16*)C)[ci] = f2bf(acc[m][n][r]);
            }
}

// ---------------- RoPE on Q in place: q[b][s][h*64], pairs (2i,2i+1) ----------------
__global__ __launch_bounds__(256) void rope_q(u16* __restrict__ q,
                                              const float* __restrict__ fc,
                                              const float* __restrict__ fs) {
    int idx = blockIdx.x * 256 + threadIdx.x;  // pair index over (b,s,h,i) : 2*2048*32*32
    int i = idx & 31;
    int s = (idx >> 10) & 2047;
    unsigned int v = ((unsigned int*)q)[idx];
    float a = bf2f((u16)(v & 0xffff)), b = bf2f((u16)(v >> 16));
    float c = fc[s * 32 + i], sn = fs[s * 32 + i];
    unsigned int o = (unsigned int)f2bf(a * c - b * sn) |
                     ((unsigned int)f2bf(a * sn + b * c) << 16);
    ((unsigned int*)q)[idx] = o;
}

// ------- RoPE on K part of kv[4096][1024] -> kb[b][g][s][64] -------
__global__ __launch_bounds__(256) void rope_k_pack(const u16* __restrict__ kv,
                                                   const float* __restrict__ fc,
                                                   const float* __restrict__ fs,
                                                   u16* __restrict__ kb) {
    int idx = blockIdx.x * 256 + threadIdx.x;  // pair idx over (b,s,g,i): 2*2048*8*32
    int i = idx & 31;
    int g = (idx >> 5) & 7;
    int s = (idx >> 8) & 2047;
    int b = idx >> 19;
    unsigned int v = ((const unsigned int*)kv)[(size_t)(b * 2048 + s) * 512 + g * 32 + i];
    float a = bf2f((u16)(v & 0xffff)), bb = bf2f((u16)(v >> 16));
    float c = fc[s * 32 + i], sn = fs[s * 32 + i];
    unsigned int o = (unsigned int)f2bf(a * c - bb * sn) |
                     ((unsigned int)f2bf(a * sn + bb * c) << 16);
    ((unsigned int*)kb)[(size_t)((b * 8 + g) * 2048 + s) * 32 + i] = o;
}

// ------- V part of kv -> vt[b][g][64][2048] (transpose hd<->s) -------
__global__ __launch_bounds__(256) void v_transpose(const u16* __restrict__ kv,
                                                   u16* __restrict__ vt) {
    __shared__ u16 tile[64][65];
    const int st = blockIdx.x, g = blockIdx.y, b = blockIdx.z;
    const int lr = threadIdx.x >> 6, lc = threadIdx.x & 63;
#pragma unroll
    for (int i = 0; i < 16; i++) {
        int s = st * 64 + i * 4 + lr;
        tile[i * 4 + lr][lc] = kv[(size_t)(b * 2048 + s) * 1024 + 512 + g * 64 + lc];
    }
    __syncthreads();
#pragma unroll
    for (int i = 0; i < 16; i++) {
        int d = i * 4 + lr;
        vt[(size_t)((b * 8 + g) * 64 + d) * 2048 + st * 64 + lc] = tile[lc][d];
    }
}

// ---------------- Flash attention (causal, GQA 4:1) ----------------
// grid (32 qtiles, 32 heads, 2 batch); 4 waves x 16 q-rows, KVBLK=64.
__global__ __launch_bounds__(256) void flash(const u16* __restrict__ Q,
                                             const u16* __restrict__ Kb,
                                             const u16* __restrict__ Vt,
                                             u16* __restrict__ O) {
    __shared__ u16 P[4][1024];  // per-wave 16x64 bf16, XOR-swizzled
    const int b = blockIdx.z, h = blockIdx.y;
    const int qt = 31 - blockIdx.x;  // long blocks dispatch first
    const int g = h >> 2;
    const int wave = threadIdx.x >> 6, lane = threadIdx.x & 63;
    const int l15 = lane & 15, l16 = lane >> 4;
    const int q0 = qt * 64 + wave * 16;

    // Q fragment (rows q0+l15, k = c*32 + l16*8 + j), pre-scaled by 1/sqrt(64)
    bf16x8 qf[2];
    {
        const u16* qp = Q + (size_t)(b * 2048 + q0 + l15) * 2048 + h * 64 + l16 * 8;
#pragma unroll
        for (int c = 0; c < 2; c++) {
            bf16x8 v = *(const bf16x8*)(qp + c * 32);
#pragma unroll
            for (int j = 0; j < 8; j++) v[j] = (__bf16)((float)v[j] * 0.125f);
            qf[c] = v;
        }
    }

    f32x4 o[4] = {};
    float mr[4] = {-1e30f, -1e30f, -1e30f, -1e30f};
    float ls[4] = {0.f, 0.f, 0.f, 0.f};
    const u16* Kg = Kb + (size_t)(b * 8 + g) * 2048 * 64;
    const u16* Vg = Vt + (size_t)(b * 8 + g) * 64 * 2048;

    for (int kt = 0; kt <= qt; kt++) {
        // ---- scores: 4 k-subtiles of 16, each 2 MFMAs over hd ----
        f32x4 sc[4];
#pragma unroll
        for (int sub = 0; sub < 4; sub++) {
            f32x4 t = {0.f, 0.f, 0.f, 0.f};
#pragma unroll
            for (int c = 0; c < 2; c++) {
                bf16x8 kf = *(const bf16x8*)(Kg + (size_t)(kt * 64 + sub * 16 + l15) * 64 +
                                             c * 32 + l16 * 8);
                t = MFMA16(qf[c], kf, t);
            }
            sc[sub] = t;
        }
        if (kt == qt) {  // causal mask on diagonal tile
#pragma unroll
            for (int sub = 0; sub < 4; sub++)
#pragma unroll
                for (int r = 0; r < 4; r++) {
                    int kcol = kt * 64 + sub * 16 + l15;
                    int qrow = q0 + l16 * 4 + r;
                    if (kcol > qrow) sc[sub][r] = -1e30f;
                }
        }
        // ---- online softmax ----
        float mx[4];
#pragma unroll
        for (int r = 0; r < 4; r++)
            mx[r] = fmaxf(fmaxf(sc[0][r], sc[1][r]), fmaxf(sc[2][r], sc[3][r]));
#pragma unroll
        for (int d = 1; d < 16; d <<= 1)
#pragma unroll
            for (int r = 0; r < 4; r++) mx[r] = fmaxf(mx[r], __shfl_xor(mx[r], d));
        float al[4];
#pragma unroll
        for (int r = 0; r < 4; r++) {
            float mn = fmaxf(mr[r], mx[r]);
            al[r] = __expf(mr[r] - mn);
            mr[r] = mn;
        }
        float rs[4] = {0.f, 0.f, 0.f, 0.f};
#pragma unroll
        for (int sub = 0; sub < 4; sub++)
#pragma unroll
            for (int r = 0; r < 4; r++) {
                float p = __expf(sc[sub][r] - mr[r]);
                sc[sub][r] = p;
                rs[r] += p;
            }
#pragma unroll
        for (int d = 1; d < 16; d <<= 1)
#pragma unroll
            for (int r = 0; r < 4; r++) rs[r] += __shfl_xor(rs[r], d);
#pragma unroll
        for (int r = 0; r < 4; r++) ls[r] = ls[r] * al[r] + rs[r];
#pragma unroll
        for (int n = 0; n < 4; n++)
#pragma unroll
            for (int r = 0; r < 4; r++) o[n][r] *= al[r];
        // ---- P -> LDS (XOR swizzle vs 128B-row bank conflict) ----
#pragma unroll
        for (int sub = 0; sub < 4; sub++)
#pragma unroll
            for (int r = 0; r < 4; r++) {
                int row = l16 * 4 + r, col = sub * 16 + l15;
                P[wave][row * 64 + (col ^ ((row & 7) << 3))] = f2bf(sc[sub][r]);
            }
        // ---- PV: o += P(16x64) * V(64x64) ----
#pragma unroll
        for (int c = 0; c < 2; c++) {
            bf16x8 pa =
                *(const bf16x8*)&P[wave][l15 * 64 + ((c * 32 + l16 * 8) ^ ((l15 & 7) << 3))];
#pragma unroll
            for (int n = 0; n < 4; n++) {
                bf16x8 vf = *(const bf16x8*)(Vg + (size_t)(n * 16 + l15) * 2048 + kt * 64 +
                                             c * 32 + l16 * 8);
                o[n] = MFMA16(pa, vf, o[n]);
            }
        }
    }
    // ---- epilogue: normalize and store bf16 ----
#pragma unroll
    for (int n = 0; n < 4; n++)
#pragma unroll
        for (int r = 0; r < 4; r++) {
            size_t oi = (size_t)(b * 2048 + q0 + l16 * 4 + r) * 2048 + h * 64 + n * 16 + l15;
            O[oi] = f2bf(o[n][r] / ls[r]);
        }
}

extern "C" void kernel_launch(void* const* d_in, const int* in_sizes, int n_in,
                              void* d_out, int out_size, void* d_ws, size_t ws_size,
                              hipStream_t stream) {
    const float* x = (const float*)d_in[0];
    const float* fc = (const float*)d_in[1];
    const float* fs = (const float*)d_in[2];
    const float* wq = (const float*)d_in[4];
    const float* wk = (const float*)d_in[5];
    const float* wv = (const float*)d_in[6];
    const float* wo = (const float*)d_in[7];
    float* out = (float*)d_out;

    u16* ws = (u16*)d_ws;
    u16* xb = ws;                                   // [4096][2048]  (reused as ab later)
    u16* wq_t = xb + (size_t)4096 * 2048;           // [2048][2048]
    u16* wkv_t = wq_t + (size_t)2048 * 2048;        // [1024][2048] (K rows 0-511, V rows 512-1023)
    u16* wo_t = wkv_t + (size_t)1024 * 2048;        // [2048][2048]
    u16* qb = wo_t + (size_t)2048 * 2048;           // [4096][2048]
    u16* kvb = qb + (size_t)4096 * 2048;            // [4096][1024]
    u16* kb = kvb + (size_t)4096 * 1024;            // [2][8][2048][64]
    u16* vt = kb + (size_t)2 * 8 * 2048 * 64;       // [2][8][64][2048]
    u16* ab = xb;                                   // alias: x-bf16 dead after QKV gemms

    cast_bf16<<<8192, 256, 0, stream>>>(x, xb, 4096 * 2048 / 4);
    transpose_cast<<<dim3(32, 32), 256, 0, stream>>>(wq, wq_t, 2048, 2048);
    transpose_cast<<<dim3(8, 32), 256, 0, stream>>>(wk, wkv_t, 2048, 512);
    transpose_cast<<<dim3(8, 32), 256, 0, stream>>>(wv, wkv_t + (size_t)512 * 2048, 2048, 512);
    transpose_cast<<<dim3(32, 32), 256, 0, stream>>>(wo, wo_t, 2048, 2048);

    gemm_bt<0><<<dim3(16, 32), 256, 0, stream>>>(xb, wq_t, qb, 4096, 2048, 2048);
    gemm_bt<0><<<dim3(8, 32), 256, 0, stream>>>(xb, wkv_t, kvb, 4096, 1024, 2048);

    rope_q<<<16384, 256, 0, stream>>>(qb, fc, fs);
    rope_k_pack<<<4096, 256, 0, stream>>>(kvb, fc, fs, kb);
    v_transpose<<<dim3(32, 8, 2), 256, 0, stream>>>(kvb, vt);

    flash<<<dim3(32, 32, 2), 256, 0, stream>>>(qb, kb, vt, ab);

    gemm_bt<1><<<dim3(16, 32), 256, 0, stream>>>(ab, wo_t, out, 4096, 2048, 2048);
}

// Round 11
// 425.445 us; speedup vs baseline: 1.7796x; 1.7796x over previous
//
#include <hip/hip_runtime.h>
#include <hip/hip_bf16.h>

typedef unsigned short u16;
typedef __bf16 bf16x8 __attribute__((ext_vector_type(8)));
typedef float f32x4 __attribute__((ext_vector_type(4)));
typedef u16 u16x4 __attribute__((ext_vector_type(4)));

__device__ __forceinline__ u16 f2bf(float f) {
    __bf16 h = (__bf16)f;
    return __builtin_bit_cast(u16, h);
}
__device__ __forceinline__ float bf2f(u16 u) {
    __bf16 h = __builtin_bit_cast(__bf16, u);
    return (float)h;
}

#define MFMA16(a, b, c) __builtin_amdgcn_mfma_f32_16x16x32_bf16(a, b, c, 0, 0, 0)

__device__ __forceinline__ void gload_lds16(const u16* g, u16* l) {
    __builtin_amdgcn_global_load_lds((const __attribute__((address_space(1))) void*)g,
                                     (__attribute__((address_space(3))) void*)l, 16, 0, 0);
}

// ---------------- cast x -> bf16 (vectorized x4) ----------------
__global__ __launch_bounds__(256) void cast_bf16(const float* __restrict__ in,
                                                 u16* __restrict__ out, int n4) {
    int i = blockIdx.x * 256 + threadIdx.x;
    if (i >= n4) return;
    float4 a = ((const float4*)in)[i];
    u16x4 u;
    u[0] = f2bf(a.x); u[1] = f2bf(a.y); u[2] = f2bf(a.z); u[3] = f2bf(a.w);
    ((u16x4*)out)[i] = u;
}

// ------------- transpose + cast: in[R][C] fp32 -> out[C][R] bf16 -------------
__global__ __launch_bounds__(256) void transpose_cast(const float* __restrict__ in,
                                                      u16* __restrict__ out, int R, int C) {
    __shared__ u16 tile[64][65];
    const int tc = blockIdx.x * 64, tr = blockIdx.y * 64;
    const int lr = threadIdx.x >> 6, lc = threadIdx.x & 63;
#pragma unroll
    for (int i = 0; i < 16; i++) {
        int r = i * 4 + lr;
        tile[r][lc] = f2bf(in[(size_t)(tr + r) * C + tc + lc]);
    }
    __syncthreads();
#pragma unroll
    for (int i = 0; i < 16; i++) {
        int r = i * 4 + lr;
        out[(size_t)(tc + r) * R + tr + lc] = tile[lc][r];
    }
}

// ---------------- GEMM: C[M,N] = A[M,K] * Bt[N,K]^T  (bf16 in, f32 acc) ----------------
// 128x128 tile, BK=32, 4 waves (2x2), 4x4 16x16x32 MFMA frags per wave.
template <int F32OUT>
__global__ __launch_bounds__(256) void gemm_bt(const u16* __restrict__ A,
                                               const u16* __restrict__ Bt,
                                               void* __restrict__ C, int M, int N, int K) {
    __shared__ u16 As[128 * 32];
    __shared__ u16 Bs[128 * 32];
    const int tid = threadIdx.x;
    const int wave = tid >> 6, lane = tid & 63;
    const int l15 = lane & 15, l16 = lane >> 4;
    const int row0 = blockIdx.y * 128, col0 = blockIdx.x * 128;
    const int wr = (wave >> 1) * 64, wc = (wave & 1) * 64;
    const int c0 = wave * 128 + lane;
    const int c1 = c0 + 64;
    const int rA0 = c0 >> 2, ccA0 = (c0 & 3) * 8;
    const int rA1 = c1 >> 2, ccA1 = (c1 & 3) * 8;
    const u16* Ab = A + (size_t)row0 * K;
    const u16* Bb = Bt + (size_t)col0 * K;

    f32x4 acc[4][4] = {};

    for (int kt = 0; kt < K; kt += 32) {
        __syncthreads();
        gload_lds16(Ab + (size_t)rA0 * K + kt + ccA0, &As[(wave * 2 + 0) * 512]);
        gload_lds16(Ab + (size_t)rA1 * K + kt + ccA1, &As[(wave * 2 + 1) * 512]);
        gload_lds16(Bb + (size_t)rA0 * K + kt + ccA0, &Bs[(wave * 2 + 0) * 512]);
        gload_lds16(Bb + (size_t)rA1 * K + kt + ccA1, &Bs[(wave * 2 + 1) * 512]);
        __syncthreads();
        bf16x8 af[4], bfr[4];
#pragma unroll
        for (int m = 0; m < 4; m++)
            af[m] = *(const bf16x8*)&As[(wr + m * 16 + l15) * 32 + l16 * 8];
#pragma unroll
        for (int n = 0; n < 4; n++)
            bfr[n] = *(const bf16x8*)&Bs[(wc + n * 16 + l15) * 32 + l16 * 8];
#pragma unroll
        for (int m = 0; m < 4; m++)
#pragma unroll
            for (int n = 0; n < 4; n++)
                acc[m][n] = MFMA16(af[m], bfr[n], acc[m][n]);
    }

#pragma unroll
    for (int m = 0; m < 4; m++)
#pragma unroll
        for (int n = 0; n < 4; n++)
#pragma unroll
            for (int r = 0; r < 4; r++) {
                size_t ci = (size_t)(row0 + wr + m * 16 + l16 * 4 + r) * N +
                            (col0 + wc + n * 16 + l15);
                if (F32OUT)
                    ((float*)C)[ci] = acc[m][n][r];
                else
                    ((u16*)C)[ci] = f2bf(acc[m][n][r]);
            }
}

// ---------------- RoPE on Q in place: q[b][s][h*64], pairs (2i,2i+1) ----------------
__global__ __launch_bounds__(256) void rope_q(u16* __restrict__ q,
                                              const float* __restrict__ fc,
                                              const float* __restrict__ fs) {
    int idx = blockIdx.x * 256 + threadIdx.x;  // pair index over (b,s,h,i) : 2*2048*32*32
    int i = idx & 31;
    int s = (idx >> 10) & 2047;
    unsigned int v = ((unsigned int*)q)[idx];
    float a = bf2f((u16)(v & 0xffff)), b = bf2f((u16)(v >> 16));
    float c = fc[s * 32 + i], sn = fs[s * 32 + i];
    unsigned int o = (unsigned int)f2bf(a * c - b * sn) |
                     ((unsigned int)f2bf(a * sn + b * c) << 16);
    ((unsigned int*)q)[idx] = o;
}

// ------- RoPE on K part of kv[4096][1024] -> kb[b][g][s][64] -------
__global__ __launch_bounds__(256) void rope_k_pack(const u16* __restrict__ kv,
                                                   const float* __restrict__ fc,
                                                   const float* __restrict__ fs,
                                                   u16* __restrict__ kb) {
    int idx = blockIdx.x * 256 + threadIdx.x;  // pair idx over (b,s,g,i): 2*2048*8*32
    int i = idx & 31;
    int g = (idx >> 5) & 7;
    int s = (idx >> 8) & 2047;
    int b = idx >> 19;
    unsigned int v = ((const unsigned int*)kv)[(size_t)(b * 2048 + s) * 512 + g * 32 + i];
    float a = bf2f((u16)(v & 0xffff)), bb = bf2f((u16)(v >> 16));
    float c = fc[s * 32 + i], sn = fs[s * 32 + i];
    unsigned int o = (unsigned int)f2bf(a * c - bb * sn) |
                     ((unsigned int)f2bf(a * sn + bb * c) << 16);
    ((unsigned int*)kb)[(size_t)((b * 8 + g) * 2048 + s) * 32 + i] = o;
}

// ------- V part of kv -> vt[b][g][64][2048] (transpose hd<->s) -------
__global__ __launch_bounds__(256) void v_transpose(const u16* __restrict__ kv,
                                                   u16* __restrict__ vt) {
    __shared__ u16 tile[64][65];
    const int st = blockIdx.x, g = blockIdx.y, b = blockIdx.z;
    const int lr = threadIdx.x >> 6, lc = threadIdx.x & 63;
#pragma unroll
    for (int i = 0; i < 16; i++) {
        int s = st * 64 + i * 4 + lr;
        tile[i * 4 + lr][lc] = kv[(size_t)(b * 2048 + s) * 1024 + 512 + g * 64 + lc];
    }
    __syncthreads();
#pragma unroll
    for (int i = 0; i < 16; i++) {
        int d = i * 4 + lr;
        vt[(size_t)((b * 8 + g) * 64 + d) * 2048 + st * 64 + lc] = tile[lc][d];
    }
}

// ---------------- Flash attention v2: 8 waves x 32 q-rows, LDS dbuf K/V ----------------
// grid (8 qtiles, 32 heads, 2 batch), 512 threads.
// qt mapping: z ? x : 7-x, so blocks i and i+256 (likely same CU under round-robin
// dispatch at 2 blocks/CU) carry complementary work (36 tiles total), not pessimal 2x-heavy.
// K/V LDS layout XOR-swizzled: 16B chunk j of row r lives at slot j^(r&7)
// (linear gload_lds dest + pre-swizzled global source, swizzled ds_read).
__global__ __launch_bounds__(512) void flash(const u16* __restrict__ Q,
                                             const u16* __restrict__ Kb,
                                             const u16* __restrict__ Vt,
                                             u16* __restrict__ O) {
    __shared__ u16 Ks[2][4096];   // [buf][64 kv x 64 hd]
    __shared__ u16 Vs[2][4096];   // [buf][64 hd x 64 kv]
    __shared__ u16 Pl[8][2048];   // per-wave 32 q x 64 kv, swizzled
    const int b = blockIdx.z, h = blockIdx.y;
    const int qt = blockIdx.z ? blockIdx.x : 7 - blockIdx.x;  // complementary pairing
    const int g = h >> 2;
    const int wave = threadIdx.x >> 6, lane = threadIdx.x & 63;
    const int l15 = lane & 15, l16 = lane >> 4;
    const int sw = l15 & 7;
    const int q0 = qt * 256 + wave * 32;
    const int KT = qt * 4 + 4;

    const u16* Kg = Kb + (size_t)(b * 8 + g) * 2048 * 64;
    const u16* Vg = Vt + (size_t)(b * 8 + g) * 64 * 2048;

    // staging addresses (lane-constant part); chunk = wave, rows wave*8+rloc
    const int rloc = lane >> 3;
    const int jg = (lane & 7) ^ rloc;  // pre-swizzled source chunk
    const u16* gK = Kg + (size_t)(wave * 8 + rloc) * 64 + jg * 8;
    const u16* gV = Vg + (size_t)(wave * 8 + rloc) * 2048 + jg * 8;

    // Q fragments: rows q0 + m*16 + l15, k = cc*32 + l16*8 + j, pre-scaled
    bf16x8 qf[2][2];
#pragma unroll
    for (int m = 0; m < 2; m++) {
        const u16* qp = Q + (size_t)(b * 2048 + q0 + m * 16 + l15) * 2048 + h * 64 + l16 * 8;
#pragma unroll
        for (int cc = 0; cc < 2; cc++) {
            bf16x8 v = *(const bf16x8*)(qp + cc * 32);
#pragma unroll
            for (int j = 0; j < 8; j++) v[j] = (__bf16)((float)v[j] * 0.125f);
            qf[m][cc] = v;
        }
    }

    f32x4 o[2][4] = {};
    float mr[2][4], ls[2][4];
#pragma unroll
    for (int m = 0; m < 2; m++)
#pragma unroll
        for (int r = 0; r < 4; r++) { mr[m][r] = -1e30f; ls[m][r] = 0.f; }
    u16* Pw = Pl[wave];

    // prologue: stage tile 0
    gload_lds16(gK, &Ks[0][wave * 512]);
    gload_lds16(gV, &Vs[0][wave * 512]);
    __syncthreads();

    for (int kt = 0; kt < KT; kt++) {
        const int cur = kt & 1;
        if (kt + 1 < KT) {  // prefetch next tile into other buffer
            gload_lds16(gK + (size_t)(kt + 1) * 4096, &Ks[cur ^ 1][wave * 512]);
            gload_lds16(gV + (kt + 1) * 64, &Vs[cur ^ 1][wave * 512]);
        }
        if (kt * 64 <= q0 + 31) {  // not fully masked for this wave
            // ---- S = Q(32x64) K^T : 16 MFMAs ----
            f32x4 s[2][4];
#pragma unroll
            for (int m = 0; m < 2; m++)
#pragma unroll
                for (int sub = 0; sub < 4; sub++) s[m][sub] = (f32x4){0.f, 0.f, 0.f, 0.f};
#pragma unroll
            for (int sub = 0; sub < 4; sub++) {
                const int krow = sub * 16 + l15;
#pragma unroll
                for (int cc = 0; cc < 2; cc++) {
                    bf16x8 kf =
                        *(const bf16x8*)&Ks[cur][krow * 64 + (((cc * 4 + l16) ^ sw) * 8)];
                    s[0][sub] = MFMA16(qf[0][cc], kf, s[0][sub]);
                    s[1][sub] = MFMA16(qf[1][cc], kf, s[1][sub]);
                }
            }
            if (kt * 64 + 63 > q0) {  // diagonal tile: causal mask
#pragma unroll
                for (int sub = 0; sub < 4; sub++)
#pragma unroll
                    for (int m = 0; m < 2; m++)
#pragma unroll
                        for (int r = 0; r < 4; r++) {
                            int kcol = kt * 64 + sub * 16 + l15;
                            int qrow = q0 + m * 16 + l16 * 4 + r;
                            if (kcol > qrow) s[m][sub][r] = -1e30f;
                        }
            }
            // ---- online softmax ----
            float mx[2][4];
#pragma unroll
            for (int m = 0; m < 2; m++)
#pragma unroll
                for (int r = 0; r < 4; r++)
                    mx[m][r] = fmaxf(fmaxf(s[m][0][r], s[m][1][r]),
                                     fmaxf(s[m][2][r], s[m][3][r]));
#pragma unroll
            for (int d = 1; d < 16; d <<= 1)
#pragma unroll
                for (int m = 0; m < 2; m++)
#pragma unroll
                    for (int r = 0; r < 4; r++)
                        mx[m][r] = fmaxf(mx[m][r], __shfl_xor(mx[m][r], d));
            float al[2][4];
#pragma unroll
            for (int m = 0; m < 2; m++)
#pragma unroll
                for (int r = 0; r < 4; r++) {
                    float mn = fmaxf(mr[m][r], mx[m][r]);
                    al[m][r] = __expf(mr[m][r] - mn);
                    mr[m][r] = mn;
                }
            float rs[2][4] = {};
#pragma unroll
            for (int sub = 0; sub < 4; sub++)
#pragma unroll
                for (int m = 0; m < 2; m++)
#pragma unroll
                    for (int r = 0; r < 4; r++) {
                        float p = __expf(s[m][sub][r] - mr[m][r]);
                        s[m][sub][r] = p;
                        rs[m][r] += p;
                    }
#pragma unroll
            for (int d = 1; d < 16; d <<= 1)
#pragma unroll
                for (int m = 0; m < 2; m++)
#pragma unroll
                    for (int r = 0; r < 4; r++) rs[m][r] += __shfl_xor(rs[m][r], d);
#pragma unroll
            for (int m = 0; m < 2; m++)
#pragma unroll
                for (int r = 0; r < 4; r++) ls[m][r] = ls[m][r] * al[m][r] + rs[m][r];
#pragma unroll
            for (int m = 0; m < 2; m++)
#pragma unroll
                for (int n = 0; n < 4; n++)
#pragma unroll
                    for (int r = 0; r < 4; r++) o[m][n][r] *= al[m][r];
            // ---- P -> LDS (swizzled) ----
#pragma unroll
            for (int sub = 0; sub < 4; sub++)
#pragma unroll
                for (int m = 0; m < 2; m++)
#pragma unroll
                    for (int r = 0; r < 4; r++) {
                        int row = m * 16 + l16 * 4 + r, col = sub * 16 + l15;
                        Pw[row * 64 + (((col >> 3) ^ (row & 7)) * 8) + (col & 7)] =
                            f2bf(s[m][sub][r]);
                    }
            // ---- PV: o(32x64) += P(32x64) V(64x64) : 16 MFMAs ----
#pragma unroll
            for (int cc = 0; cc < 2; cc++) {
                bf16x8 pa0 = *(const bf16x8*)&Pw[l15 * 64 + (((cc * 4 + l16) ^ sw) * 8)];
                bf16x8 pa1 =
                    *(const bf16x8*)&Pw[(16 + l15) * 64 + (((cc * 4 + l16) ^ sw) * 8)];
#pragma unroll
                for (int n = 0; n < 4; n++) {
                    const int vrow = n * 16 + l15;
                    bf16x8 vf =
                        *(const bf16x8*)&Vs[cur][vrow * 64 + (((cc * 4 + l16) ^ sw) * 8)];
                    o[0][n] = MFMA16(pa0, vf, o[0][n]);
                    o[1][n] = MFMA16(pa1, vf, o[1][n]);
                }
            }
        }
        __syncthreads();  // drains vmcnt(0): next tile staged; all compute on cur done
    }
    // ---- epilogue ----
#pragma unroll
    for (int m = 0; m < 2; m++)
#pragma unroll
        for (int r = 0; r < 4; r++) {
            float inv = 1.f / ls[m][r];
#pragma unroll
            for (int n = 0; n < 4; n++) {
                size_t oi = (size_t)(b * 2048 + q0 + m * 16 + l16 * 4 + r) * 2048 + h * 64 +
                            n * 16 + l15;
                O[oi] = f2bf(o[m][n][r] * inv);
            }
        }
}

extern "C" void kernel_launch(void* const* d_in, const int* in_sizes, int n_in,
                              void* d_out, int out_size, void* d_ws, size_t ws_size,
                              hipStream_t stream) {
    const float* x = (const float*)d_in[0];
    const float* fc = (const float*)d_in[1];
    const float* fs = (const float*)d_in[2];
    const float* wq = (const float*)d_in[4];
    const float* wk = (const float*)d_in[5];
    const float* wv = (const float*)d_in[6];
    const float* wo = (const float*)d_in[7];
    float* out = (float*)d_out;

    u16* ws = (u16*)d_ws;
    u16* xb = ws;                                   // [4096][2048]  (reused as ab later)
    u16* wq_t = xb + (size_t)4096 * 2048;           // [2048][2048]
    u16* wkv_t = wq_t + (size_t)2048 * 2048;        // [1024][2048]
    u16* wo_t = wkv_t + (size_t)1024 * 2048;        // [2048][2048]
    u16* qb = wo_t + (size_t)2048 * 2048;           // [4096][2048]
    u16* kvb = qb + (size_t)4096 * 2048;            // [4096][1024]
    u16* kb = kvb + (size_t)4096 * 1024;            // [2][8][2048][64]
    u16* vt = kb + (size_t)2 * 8 * 2048 * 64;       // [2][8][64][2048]
    u16* ab = xb;                                   // alias: x-bf16 dead after QKV gemms

    cast_bf16<<<8192, 256, 0, stream>>>(x, xb, 4096 * 2048 / 4);
    transpose_cast<<<dim3(32, 32), 256, 0, stream>>>(wq, wq_t, 2048, 2048);
    transpose_cast<<<dim3(8, 32), 256, 0, stream>>>(wk, wkv_t, 2048, 512);
    transpose_cast<<<dim3(8, 32), 256, 0, stream>>>(wv, wkv_t + (size_t)512 * 2048, 2048, 512);
    transpose_cast<<<dim3(32, 32), 256, 0, stream>>>(wo, wo_t, 2048, 2048);

    gemm_bt<0><<<dim3(16, 32), 256, 0, stream>>>(xb, wq_t, qb, 4096, 2048, 2048);
    gemm_bt<0><<<dim3(8, 32), 256, 0, stream>>>(xb, wkv_t, kvb, 4096, 1024, 2048);

    rope_q<<<16384, 256, 0, stream>>>(qb, fc, fs);
    rope_k_pack<<<4096, 256, 0, stream>>>(kvb, fc, fs, kb);
    v_transpose<<<dim3(32, 8, 2), 256, 0, stream>>>(kvb, vt);

    flash<<<dim3(8, 32, 2), 512, 0, stream>>>(qb, kb, vt, ab);

    gemm_bt<1><<<dim3(16, 32), 256, 0, stream>>>(ab, wo_t, out, 4096, 2048, 2048);
}

// Round 15
// 394.285 us; speedup vs baseline: 1.9203x; 1.0790x over previous
//
#include <hip/hip_runtime.h>
#include <hip/hip_bf16.h>

typedef unsigned short u16;
typedef __bf16 bf16x8 __attribute__((ext_vector_type(8)));
typedef float f32x4 __attribute__((ext_vector_type(4)));
typedef u16 u16x4 __attribute__((ext_vector_type(4)));

__device__ __forceinline__ u16 f2bf(float f) {
    __bf16 h = (__bf16)f;
    return __builtin_bit_cast(u16, h);
}
__device__ __forceinline__ float bf2f(u16 u) {
    __bf16 h = __builtin_bit_cast(__bf16, u);
    return (float)h;
}

#define MFMA16(a, b, c) __builtin_amdgcn_mfma_f32_16x16x32_bf16(a, b, c, 0, 0, 0)

__device__ __forceinline__ void gload_lds16(const u16* g, u16* l) {
    __builtin_amdgcn_global_load_lds((const __attribute__((address_space(1))) void*)g,
                                     (__attribute__((address_space(3))) void*)l, 16, 0, 0);
}

// ---------------- cast x -> bf16 (vectorized x4) ----------------
__global__ __launch_bounds__(256) void cast_bf16(const float* __restrict__ in,
                                                 u16* __restrict__ out, int n4) {
    int i = blockIdx.x * 256 + threadIdx.x;
    if (i >= n4) return;
    float4 a = ((const float4*)in)[i];
    u16x4 u;
    u[0] = f2bf(a.x); u[1] = f2bf(a.y); u[2] = f2bf(a.z); u[3] = f2bf(a.w);
    ((u16x4*)out)[i] = u;
}

// ------- transpose+cast ALL weights in one dispatch: z selects {wq,wk,wv,wo} -------
// All inputs are [2048][C] fp32; output is [C][2048] bf16 at the given base.
__global__ __launch_bounds__(256) void transpose_all(const float* __restrict__ wq,
                                                     const float* __restrict__ wk,
                                                     const float* __restrict__ wv,
                                                     const float* __restrict__ wo,
                                                     u16* __restrict__ wqkv_t,
                                                     u16* __restrict__ wo_t) {
    const int z = blockIdx.z;
    const float* in;
    u16* out;
    int C;
    if (z == 0)      { in = wq; out = wqkv_t;                     C = 2048; }
    else if (z == 1) { in = wk; out = wqkv_t + (size_t)2048 * 2048; C = 512; }
    else if (z == 2) { in = wv; out = wqkv_t + (size_t)2560 * 2048; C = 512; }
    else             { in = wo; out = wo_t;                       C = 2048; }
    if (blockIdx.x * 64 >= C) return;  // uniform per-block early-out (wk/wv use 8 x-blocks)

    __shared__ u16 tile[64][65];
    const int tc = blockIdx.x * 64, tr = blockIdx.y * 64;
    const int lr = threadIdx.x >> 6, lc = threadIdx.x & 63;
#pragma unroll
    for (int i = 0; i < 16; i++) {
        int r = i * 4 + lr;
        tile[r][lc] = f2bf(in[(size_t)(tr + r) * C + tc + lc]);
    }
    __syncthreads();
#pragma unroll
    for (int i = 0; i < 16; i++) {
        int r = i * 4 + lr;
        out[(size_t)(tc + r) * 2048 + tr + lc] = tile[lc][r];
    }
}

// ---------------- GEMM: C[M,N] = A[M,K] * Bt[N,K]^T  (bf16 in, f32 acc) ----------------
// 128x128 tile, BK=32, 4 waves (2x2), 4x4 16x16x32 MFMA frags per wave. (m97 structure)
template <int F32OUT>
__global__ __launch_bounds__(256) void gemm_bt(const u16* __restrict__ A,
                                               const u16* __restrict__ Bt,
                                               void* __restrict__ C, int M, int N, int K) {
    __shared__ u16 As[128 * 32];
    __shared__ u16 Bs[128 * 32];
    const int tid = threadIdx.x;
    const int wave = tid >> 6, lane = tid & 63;
    const int l15 = lane & 15, l16 = lane >> 4;
    const int row0 = blockIdx.y * 128, col0 = blockIdx.x * 128;
    const int wr = (wave >> 1) * 64, wc = (wave & 1) * 64;
    const int c0 = wave * 128 + lane;
    const int c1 = c0 + 64;
    const int rA0 = c0 >> 2, ccA0 = (c0 & 3) * 8;
    const int rA1 = c1 >> 2, ccA1 = (c1 & 3) * 8;
    const u16* Ab = A + (size_t)row0 * K;
    const u16* Bb = Bt + (size_t)col0 * K;

    f32x4 acc[4][4] = {};

    for (int kt = 0; kt < K; kt += 32) {
        __syncthreads();
        gload_lds16(Ab + (size_t)rA0 * K + kt + ccA0, &As[(wave * 2 + 0) * 512]);
        gload_lds16(Ab + (size_t)rA1 * K + kt + ccA1, &As[(wave * 2 + 1) * 512]);
        gload_lds16(Bb + (size_t)rA0 * K + kt + ccA0, &Bs[(wave * 2 + 0) * 512]);
        gload_lds16(Bb + (size_t)rA1 * K + kt + ccA1, &Bs[(wave * 2 + 1) * 512]);
        __syncthreads();
        bf16x8 af[4], bfr[4];
#pragma unroll
        for (int m = 0; m < 4; m++)
            af[m] = *(const bf16x8*)&As[(wr + m * 16 + l15) * 32 + l16 * 8];
#pragma unroll
        for (int n = 0; n < 4; n++)
            bfr[n] = *(const bf16x8*)&Bs[(wc + n * 16 + l15) * 32 + l16 * 8];
#pragma unroll
        for (int m = 0; m < 4; m++)
#pragma unroll
            for (int n = 0; n < 4; n++)
                acc[m][n] = MFMA16(af[m], bfr[n], acc[m][n]);
    }

#pragma unroll
    for (int m = 0; m < 4; m++)
#pragma unroll
        for (int n = 0; n < 4; n++)
#pragma unroll
            for (int r = 0; r < 4; r++) {
                size_t ci = (size_t)(row0 + wr + m * 16 + l16 * 4 + r) * N +
                            (col0 + wc + n * 16 + l15);
                if (F32OUT)
                    ((float*)C)[ci] = acc[m][n][r];
                else
                    ((u16*)C)[ci] = f2bf(acc[m][n][r]);
            }
}

// ------- RoPE on Q (in place in qkv[4096][3072]) + K (qkv cols 2048.. -> kb) -------
// pair idx space: [0, 2*2048*32*32) = Q pairs; rest = K pairs.
__global__ __launch_bounds__(256) void rope_qk(u16* __restrict__ qkv,
                                               const float* __restrict__ fc,
                                               const float* __restrict__ fs,
                                               u16* __restrict__ kb) {
    int idx = blockIdx.x * 256 + threadIdx.x;
    unsigned int* q32 = (unsigned int*)qkv;
    if (idx < 2 * 2048 * 32 * 32) {  // Q: (b,s,h,i)
        int i = idx & 31;
        int h = (idx >> 5) & 31;
        int s = (idx >> 10) & 2047;
        int b = idx >> 21;
        size_t a = (size_t)(b * 2048 + s) * 1536 + h * 32 + i;
        unsigned int v = q32[a];
        float x = bf2f((u16)(v & 0xffff)), y = bf2f((u16)(v >> 16));
        float c = fc[s * 32 + i], sn = fs[s * 32 + i];
        q32[a] = (unsigned int)f2bf(x * c - y * sn) |
                 ((unsigned int)f2bf(x * sn + y * c) << 16);
    } else {  // K: (b,s,g,i) -> kb[b][g][s][64]
        int j = idx - 2 * 2048 * 32 * 32;
        int i = j & 31;
        int g = (j >> 5) & 7;
        int s = (j >> 8) & 2047;
        int b = j >> 19;
        size_t a = (size_t)(b * 2048 + s) * 1536 + 1024 + g * 32 + i;
        unsigned int v = q32[a];
        float x = bf2f((u16)(v & 0xffff)), y = bf2f((u16)(v >> 16));
        float c = fc[s * 32 + i], sn = fs[s * 32 + i];
        ((unsigned int*)kb)[(size_t)((b * 8 + g) * 2048 + s) * 32 + i] =
            (unsigned int)f2bf(x * c - y * sn) |
            ((unsigned int)f2bf(x * sn + y * c) << 16);
    }
}

// ------- V part of qkv[4096][3072] (cols 2560..3071) -> vt[b][g][64][2048] -------
__global__ __launch_bounds__(256) void v_transpose(const u16* __restrict__ qkv,
                                                   u16* __restrict__ vt) {
    __shared__ u16 tile[64][65];
    const int st = blockIdx.x, g = blockIdx.y, b = blockIdx.z;
    const int lr = threadIdx.x >> 6, lc = threadIdx.x & 63;
#pragma unroll
    for (int i = 0; i < 16; i++) {
        int s = st * 64 + i * 4 + lr;
        tile[i * 4 + lr][lc] = qkv[(size_t)(b * 2048 + s) * 3072 + 2560 + g * 64 + lc];
    }
    __syncthreads();
#pragma unroll
    for (int i = 0; i < 16; i++) {
        int d = i * 4 + lr;
        vt[(size_t)((b * 8 + g) * 64 + d) * 2048 + st * 64 + lc] = tile[lc][d];
    }
}

// ---------------- Flash attention v2.1: 8 waves x 32 q-rows, LDS dbuf K/V ----------------
// grid (8 qtiles, 32 heads, 2 batch), 512 threads. Q row stride 3072 (merged qkv buffer).
// + T5: setprio(1) around MFMA clusters.
__global__ __launch_bounds__(512) void flash(const u16* __restrict__ Q,
                                             const u16* __restrict__ Kb,
                                             const u16* __restrict__ Vt,
                                             u16* __restrict__ O) {
    __shared__ u16 Ks[2][4096];   // [buf][64 kv x 64 hd]
    __shared__ u16 Vs[2][4096];   // [buf][64 hd x 64 kv]
    __shared__ u16 Pl[8][2048];   // per-wave 32 q x 64 kv, swizzled
    const int b = blockIdx.z, h = blockIdx.y;
    const int qt = blockIdx.z ? blockIdx.x : 7 - blockIdx.x;  // complementary pairing
    const int g = h >> 2;
    const int wave = threadIdx.x >> 6, lane = threadIdx.x & 63;
    const int l15 = lane & 15, l16 = lane >> 4;
    const int sw = l15 & 7;
    const int q0 = qt * 256 + wave * 32;
    const int KT = qt * 4 + 4;

    const u16* Kg = Kb + (size_t)(b * 8 + g) * 2048 * 64;
    const u16* Vg = Vt + (size_t)(b * 8 + g) * 64 * 2048;

    const int rloc = lane >> 3;
    const int jg = (lane & 7) ^ rloc;  // pre-swizzled source chunk
    const u16* gK = Kg + (size_t)(wave * 8 + rloc) * 64 + jg * 8;
    const u16* gV = Vg + (size_t)(wave * 8 + rloc) * 2048 + jg * 8;

    // Q fragments: rows q0 + m*16 + l15, k = cc*32 + l16*8 + j, pre-scaled
    bf16x8 qf[2][2];
#pragma unroll
    for (int m = 0; m < 2; m++) {
        const u16* qp = Q + (size_t)(b * 2048 + q0 + m * 16 + l15) * 3072 + h * 64 + l16 * 8;
#pragma unroll
        for (int cc = 0; cc < 2; cc++) {
            bf16x8 v = *(const bf16x8*)(qp + cc * 32);
#pragma unroll
            for (int j = 0; j < 8; j++) v[j] = (__bf16)((float)v[j] * 0.125f);
            qf[m][cc] = v;
        }
    }

    f32x4 o[2][4] = {};
    float mr[2][4], ls[2][4];
#pragma unroll
    for (int m = 0; m < 2; m++)
#pragma unroll
        for (int r = 0; r < 4; r++) { mr[m][r] = -1e30f; ls[m][r] = 0.f; }
    u16* Pw = Pl[wave];

    gload_lds16(gK, &Ks[0][wave * 512]);
    gload_lds16(gV, &Vs[0][wave * 512]);
    __syncthreads();

    for (int kt = 0; kt < KT; kt++) {
        const int cur = kt & 1;
        if (kt + 1 < KT) {
            gload_lds16(gK + (size_t)(kt + 1) * 4096, &Ks[cur ^ 1][wave * 512]);
            gload_lds16(gV + (kt + 1) * 64, &Vs[cur ^ 1][wave * 512]);
        }
        if (kt * 64 <= q0 + 31) {
            // ---- S = Q(32x64) K^T : 16 MFMAs ----
            f32x4 s[2][4];
#pragma unroll
            for (int m = 0; m < 2; m++)
#pragma unroll
                for (int sub = 0; sub < 4; sub++) s[m][sub] = (f32x4){0.f, 0.f, 0.f, 0.f};
            __builtin_amdgcn_s_setprio(1);
#pragma unroll
            for (int sub = 0; sub < 4; sub++) {
                const int krow = sub * 16 + l15;
#pragma unroll
                for (int cc = 0; cc < 2; cc++) {
                    bf16x8 kf =
                        *(const bf16x8*)&Ks[cur][krow * 64 + (((cc * 4 + l16) ^ sw) * 8)];
                    s[0][sub] = MFMA16(qf[0][cc], kf, s[0][sub]);
                    s[1][sub] = MFMA16(qf[1][cc], kf, s[1][sub]);
                }
            }
            __builtin_amdgcn_s_setprio(0);
            if (kt * 64 + 63 > q0) {  // diagonal tile: causal mask
#pragma unroll
                for (int sub = 0; sub < 4; sub++)
#pragma unroll
                    for (int m = 0; m < 2; m++)
#pragma unroll
                        for (int r = 0; r < 4; r++) {
                            int kcol = kt * 64 + sub * 16 + l15;
                            int qrow = q0 + m * 16 + l16 * 4 + r;
                            if (kcol > qrow) s[m][sub][r] = -1e30f;
                        }
            }
            // ---- online softmax ----
            float mx[2][4];
#pragma unroll
            for (int m = 0; m < 2; m++)
#pragma unroll
                for (int r = 0; r < 4; r++)
                    mx[m][r] = fmaxf(fmaxf(s[m][0][r], s[m][1][r]),
                                     fmaxf(s[m][2][r], s[m][3][r]));
#pragma unroll
            for (int d = 1; d < 16; d <<= 1)
#pragma unroll
                for (int m = 0; m < 2; m++)
#pragma unroll
                    for (int r = 0; r < 4; r++)
                        mx[m][r] = fmaxf(mx[m][r], __shfl_xor(mx[m][r], d));
            float al[2][4];
#pragma unroll
            for (int m = 0; m < 2; m++)
#pragma unroll
                for (int r = 0; r < 4; r++) {
                    float mn = fmaxf(mr[m][r], mx[m][r]);
                    al[m][r] = __expf(mr[m][r] - mn);
                    mr[m][r] = mn;
                }
            float rs[2][4] = {};
#pragma unroll
            for (int sub = 0; sub < 4; sub++)
#pragma unroll
                for (int m = 0; m < 2; m++)
#pragma unroll
                    for (int r = 0; r < 4; r++) {
                        float p = __expf(s[m][sub][r] - mr[m][r]);
                        s[m][sub][r] = p;
                        rs[m][r] += p;
                    }
#pragma unroll
            for (int d = 1; d < 16; d <<= 1)
#pragma unroll
                for (int m = 0; m < 2; m++)
#pragma unroll
                    for (int r = 0; r < 4; r++) rs[m][r] += __shfl_xor(rs[m][r], d);
#pragma unroll
            for (int m = 0; m < 2; m++)
#pragma unroll
                for (int r = 0; r < 4; r++) ls[m][r] = ls[m][r] * al[m][r] + rs[m][r];
#pragma unroll
            for (int m = 0; m < 2; m++)
#pragma unroll
                for (int n = 0; n < 4; n++)
#pragma unroll
                    for (int r = 0; r < 4; r++) o[m][n][r] *= al[m][r];
            // ---- P -> LDS (swizzled) ----
#pragma unroll
            for (int sub = 0; sub < 4; sub++)
#pragma unroll
                for (int m = 0; m < 2; m++)
#pragma unroll
                    for (int r = 0; r < 4; r++) {
                        int row = m * 16 + l16 * 4 + r, col = sub * 16 + l15;
                        Pw[row * 64 + (((col >> 3) ^ (row & 7)) * 8) + (col & 7)] =
                            f2bf(s[m][sub][r]);
                    }
            // ---- PV: o(32x64) += P(32x64) V(64x64) : 16 MFMAs ----
            __builtin_amdgcn_s_setprio(1);
#pragma unroll
            for (int cc = 0; cc < 2; cc++) {
                bf16x8 pa0 = *(const bf16x8*)&Pw[l15 * 64 + (((cc * 4 + l16) ^ sw) * 8)];
                bf16x8 pa1 =
                    *(const bf16x8*)&Pw[(16 + l15) * 64 + (((cc * 4 + l16) ^ sw) * 8)];
#pragma unroll
                for (int n = 0; n < 4; n++) {
                    const int vrow = n * 16 + l15;
                    bf16x8 vf =
                        *(const bf16x8*)&Vs[cur][vrow * 64 + (((cc * 4 + l16) ^ sw) * 8)];
                    o[0][n] = MFMA16(pa0, vf, o[0][n]);
                    o[1][n] = MFMA16(pa1, vf, o[1][n]);
                }
            }
            __builtin_amdgcn_s_setprio(0);
        }
        __syncthreads();
    }
    // ---- epilogue: O row stride 2048 ----
#pragma unroll
    for (int m = 0; m < 2; m++)
#pragma unroll
        for (int r = 0; r < 4; r++) {
            float inv = 1.f / ls[m][r];
#pragma unroll
            for (int n = 0; n < 4; n++) {
                size_t oi = (size_t)(b * 2048 + q0 + m * 16 + l16 * 4 + r) * 2048 + h * 64 +
                            n * 16 + l15;
                O[oi] = f2bf(o[m][n][r] * inv);
            }
        }
}

extern "C" void kernel_launch(void* const* d_in, const int* in_sizes, int n_in,
                              void* d_out, int out_size, void* d_ws, size_t ws_size,
                              hipStream_t stream) {
    const float* x = (const float*)d_in[0];
    const float* fc = (const float*)d_in[1];
    const float* fs = (const float*)d_in[2];
    const float* wq = (const float*)d_in[4];
    const float* wk = (const float*)d_in[5];
    const float* wv = (const float*)d_in[6];
    const float* wo = (const float*)d_in[7];
    float* out = (float*)d_out;

    u16* ws = (u16*)d_ws;
    u16* xb = ws;                                    // [4096][2048]  (reused as ab later)
    u16* wqkv_t = xb + (size_t)4096 * 2048;          // [3072][2048]  (Q rows 0-2047, K 2048-2559, V 2560-3071)
    u16* wo_t = wqkv_t + (size_t)3072 * 2048;        // [2048][2048]
    u16* qkv = wo_t + (size_t)2048 * 2048;           // [4096][3072]
    u16* kb = qkv + (size_t)4096 * 3072;             // [2][8][2048][64]
    u16* vt = kb + (size_t)2 * 8 * 2048 * 64;        // [2][8][64][2048]
    u16* ab = xb;                                    // alias: x-bf16 dead after QKV gemm

    cast_bf16<<<8192, 256, 0, stream>>>(x, xb, 4096 * 2048 / 4);
    transpose_all<<<dim3(32, 32, 4), 256, 0, stream>>>(wq, wk, wv, wo, wqkv_t, wo_t);

    gemm_bt<0><<<dim3(24, 32), 256, 0, stream>>>(xb, wqkv_t, qkv, 4096, 3072, 2048);

    rope_qk<<<20480, 256, 0, stream>>>(qkv, fc, fs, kb);
    v_transpose<<<dim3(32, 8, 2), 256, 0, stream>>>(qkv, vt);

    flash<<<dim3(8, 32, 2), 512, 0, stream>>>(qkv, kb, vt, ab);

    gemm_bt<1><<<dim3(16, 32), 256, 0, stream>>>(ab, wo_t, out, 4096, 2048, 2048);
}